// Round 1
// 913.674 us; speedup vs baseline: 1.7535x; 1.7535x over previous
//
#include <hip/hip_runtime.h>
#include <hip/hip_bf16.h>

#define BB 8
#define HH 96
#define WW2 96
#define DIM 384
#define HEADS 12
#define HD 32
#define WS 12
#define DISP 6
#define NWH 8
#define NWW 8
#define NW 64
#define TPW 144           // tokens per window (12*12)
#define INNER 384         // HEADS*HD
#define NQKV 1152         // 3*INNER
#define MTOK (BB*NW*TPW)  // 73728 tokens total
#define SCALE 0.17677669529663687f

typedef short short8_t __attribute__((ext_vector_type(8)));
typedef float float4_t __attribute__((ext_vector_type(4)));
typedef unsigned short ushort8_t __attribute__((ext_vector_type(8)));
typedef unsigned short ushort4_t __attribute__((ext_vector_type(4)));

__device__ __forceinline__ float us2f(unsigned short u) {
    union { unsigned int u32; float f; } c; c.u32 = ((unsigned int)u) << 16; return c.f;
}
__device__ __forceinline__ unsigned short f2us(float f) {
    union { float f; unsigned int u; } c; c.f = f;
    unsigned int u = c.u;
    u += 0x7FFFu + ((u >> 16) & 1u);   // round-to-nearest-even
    return (unsigned short)(u >> 16);
}

// tiny: wqkvT[n][k] = bf16(wqkv[k][n])
__global__ __launch_bounds__(256) void cast_wqkvT(
    const float* __restrict__ wqkv, unsigned short* __restrict__ wqkvT)
{
    int idx = blockIdx.x * 256 + threadIdx.x;
    if (idx >= NQKV * DIM) return;
    int n = idx / DIM, k = idx - n * DIM;
    wqkvT[idx] = f2us(wqkv[k * NQKV + n]);
}

// Fused per-(b,head,window):
//   Phase A = MFMA GEMM q|k|v(144x96) = xwin(144x384) @ wT  (bf16 staging, stride-40 pad)
//   Phase B = MFMA attention: QK^T (q/k hi+lo bf16 split), in-register masked softmax,
//             PV (P hi+lo passes vs bf16 V^T). Zero barriers; waves independent.
__global__ __launch_bounds__(256, 2) void fused_attn(
    const float* __restrict__ x,
    const unsigned short* __restrict__ wqkvT,   // [1152][384] bf16
    const int* __restrict__ pix_map,
    const float* __restrict__ pos_emb,          // [23][23]
    const float* __restrict__ pix_emb,          // [2]
    unsigned short* __restrict__ ao)            // [MTOK][INNER] windowed, bf16
{
    __shared__ float qs[TPW][HD + 1];              // scaled q, fp32
    __shared__ float ks[TPW][HD + 1];              // k, fp32
    __shared__ unsigned short vt[HD][168];         // V^T bf16, cols [144,160) zeroed
    __align__(16) __shared__ char uni[23552];      // A: xw[144][40]+wcT[96][40] bf16 ; B: pscr 4x[16][184] bf16
    __shared__ float pos[529];
    __shared__ int   pmv[TPW];
    __shared__ int   rowoff[TPW];

    unsigned short* xw  = (unsigned short*)uni;            // [144][40] bf16
    unsigned short* wcT = (unsigned short*)(uni + 11520);  // [96][40] bf16

    const int tid = threadIdx.x;
    const int w = blockIdx.x, h = blockIdx.y, b = blockIdx.z;
    const int nwy = w >> 3, nww = w & 7;
    const int tbase = (b * NW + w) * TPW;

    if (tid < TPW) {
        int ri = tid / WS, ci = tid - ri * WS;
        int ys = nwy * WS + ri, xs2 = nww * WS + ci;
        int yin = ys + DISP; if (yin >= HH) yin -= HH;
        int xin = xs2 + DISP; if (xin >= WW2) xin -= WW2;
        rowoff[tid] = ((b * HH + yin) * WW2 + xin) * DIM;     // shifted gather
        pmv[tid] = pix_map[(b * HH + ys) * WW2 + xs2];        // UNshifted (ref quirk)
    }
    for (int idx = tid; idx < 529; idx += 256) pos[idx] = pos_emb[idx];
    {   // zero vt pad columns [144,160): 32 rows x 8 dwords = 256 threads
        int zr = tid >> 3, zc = tid & 7;
        *(unsigned int*)(&vt[zr][144 + zc * 2]) = 0u;
    }
    __syncthreads();

    // ---- Phase A: MFMA GEMM, 9x6 grid of 16x16x32 tiles, waves 2x2 ----
    const int wave = tid >> 6, lane = tid & 63;
    const int quad = lane >> 4, l16 = lane & 15;
    const int mw = wave >> 1, nw = wave & 1;
    const int nmt = mw ? 4 : 5;                 // m-tiles: 0..4 / 5..8
    const int mbase = mw * 5, nbase = nw * 3;

    float4_t acc[5][3];
    #pragma unroll
    for (int i = 0; i < 5; i++)
        #pragma unroll
        for (int j = 0; j < 3; j++) acc[i][j] = (float4_t){0.f, 0.f, 0.f, 0.f};

    for (int k0 = 0; k0 < DIM; k0 += 32) {
        for (int idx = tid; idx < 576; idx += 256) {          // xw: 144 rows x 4 chunks
            int r = idx >> 2, qr = idx & 3;
            const float* src = x + rowoff[r] + k0 + qr * 8;
            float4 a = *(const float4*)src;
            float4 c = *(const float4*)(src + 4);
            ushort8_t u;
            u[0] = f2us(a.x); u[1] = f2us(a.y); u[2] = f2us(a.z); u[3] = f2us(a.w);
            u[4] = f2us(c.x); u[5] = f2us(c.y); u[6] = f2us(c.z); u[7] = f2us(c.w);
            *(ushort8_t*)(xw + r * 40 + qr * 8) = u;
        }
        for (int idx = tid; idx < 384; idx += 256) {          // wcT: 96 rows x 4 chunks
            int r = idx >> 2, c = (idx & 3) << 3;
            int s = r >> 5, nn = r & 31;
            int gn = s * INNER + h * HD + nn;
            *(ushort8_t*)(wcT + r * 40 + c) =
                *(const ushort8_t*)(wqkvT + gn * DIM + k0 + c);
        }
        __syncthreads();
        short8_t afr[5], bfr[3];
        #pragma unroll
        for (int j = 0; j < 3; j++)
            bfr[j] = *(short8_t*)(wcT + ((nbase + j) * 16 + l16) * 40 + quad * 8);
        #pragma unroll
        for (int i = 0; i < 5; i++)
            if (i < nmt)
                afr[i] = *(short8_t*)(xw + ((mbase + i) * 16 + l16) * 40 + quad * 8);
        #pragma unroll
        for (int i = 0; i < 5; i++)
            if (i < nmt)
                #pragma unroll
                for (int j = 0; j < 3; j++)
                    acc[i][j] = __builtin_amdgcn_mfma_f32_16x16x32_bf16(
                        afr[i], bfr[j], acc[i][j], 0, 0, 0);
        __syncthreads();
    }
    // C writeback: D col = lane&15, row = quad*4 + reg (m89-verified layout)
    #pragma unroll
    for (int i = 0; i < 5; i++)
        if (i < nmt) {
            int tm = mbase + i;
            #pragma unroll
            for (int j = 0; j < 3; j++) {
                int tn = nbase + j;
                int s = tn >> 1;                    // 0=q, 1=k, 2=v (tile-uniform)
                int cc = ((tn & 1) << 4) | l16;
                if (s == 2) {
                    // v: transposed bf16 store, 4 consecutive cols -> one b64
                    ushort4_t pk;
                    #pragma unroll
                    for (int r = 0; r < 4; r++) pk[r] = f2us(acc[i][j][r]);
                    *(ushort4_t*)(&vt[cc][tm * 16 + quad * 4]) = pk;
                } else {
                    float* dst = (s == 0) ? &qs[0][0] : &ks[0][0];
                    float mul = (s == 0) ? SCALE : 1.0f;
                    #pragma unroll
                    for (int r = 0; r < 4; r++)
                        dst[(tm * 16 + quad * 4 + r) * (HD + 1) + cc] = acc[i][j][r] * mul;
                }
            }
        }
    __syncthreads();

    // ---- Phase B: MFMA attention, wave-private, no barriers ----
    unsigned short* pscr = (unsigned short*)uni + wave * (16 * 184);
    {   // zero pscr pad columns [144,160): 16 rows x 4 qwords = 64 lanes
        int zr = lane >> 2, zc = lane & 3;
        *(unsigned long long*)(pscr + zr * 184 + 144 + zc * 4) = 0ULL;
    }
    const float pe0 = pix_emb[0], pe1 = pix_emb[1];
    const bool ul = (nwy == NWH - 1), lr = (nww == NWW - 1);
    const int mt_start = wave ? (wave * 2 + 1) : 0;   // 0,3,5,7
    const int mt_count = wave ? 2 : 3;

    for (int it = 0; it < mt_count; ++it) {
        const int mt = mt_start + it;
        // Q hi/lo frags
        short8_t qh, ql;
        {
            const float* qrow = &qs[mt * 16 + l16][quad * 8];
            #pragma unroll
            for (int j2 = 0; j2 < 8; j2++) {
                float f = qrow[j2];
                unsigned short hh = f2us(f);
                qh[j2] = (short)hh;
                ql[j2] = (short)f2us(f - us2f(hh));
            }
        }
        // QK^T: 9 n-tiles, K hi/lo per tile, 3 MFMAs each
        float4_t s[9];
        #pragma unroll
        for (int nt = 0; nt < 9; nt++) {
            const float* krow = &ks[nt * 16 + l16][quad * 8];
            short8_t kh, kl;
            #pragma unroll
            for (int j2 = 0; j2 < 8; j2++) {
                float f = krow[j2];
                unsigned short hh = f2us(f);
                kh[j2] = (short)hh;
                kl[j2] = (short)f2us(f - us2f(hh));
            }
            float4_t a = (float4_t){0.f, 0.f, 0.f, 0.f};
            a = __builtin_amdgcn_mfma_f32_16x16x32_bf16(qh, kh, a, 0, 0, 0);
            a = __builtin_amdgcn_mfma_f32_16x16x32_bf16(ql, kh, a, 0, 0, 0);
            a = __builtin_amdgcn_mfma_f32_16x16x32_bf16(qh, kl, a, 0, 0, 0);
            s[nt] = a;
        }
        // masks + bias + rowmax (rows of this lane: i = mt*16 + quad*4 + r, cols j = nt*16+l16)
        const int ib = mt * 16 + quad * 4;
        int riA[4], ciA[4], pmA[4];
        float mx[4];
        #pragma unroll
        for (int r = 0; r < 4; r++) {
            int i = ib + r;
            riA[r] = i / 12; ciA[r] = i - riA[r] * 12;
            pmA[r] = pmv[i];
            mx[r] = -3e38f;
        }
        #pragma unroll
        for (int nt = 0; nt < 9; nt++) {
            int j = nt * 16 + l16;
            int rj = j / 12, cj = j - rj * 12;
            int pj = pmv[j];
            bool jul = (rj >= 6), jlr = (cj >= 6);
            #pragma unroll
            for (int r = 0; r < 4; r++) {
                float a = s[nt][r];
                a += pos[(rj - riA[r] + 11) * 23 + (cj - ciA[r] + 11)];
                a += (pmA[r] * pj) ? pe1 : pe0;
                if (ul && ((riA[r] >= 6) != jul)) a -= 1e30f;
                if (lr && ((ciA[r] >= 6) != jlr)) a -= 1e30f;
                s[nt][r] = a;
                mx[r] = fmaxf(mx[r], a);
            }
        }
        #pragma unroll
        for (int r = 0; r < 4; r++) {
            float m2 = mx[r];
            m2 = fmaxf(m2, __shfl_xor(m2, 1));
            m2 = fmaxf(m2, __shfl_xor(m2, 2));
            m2 = fmaxf(m2, __shfl_xor(m2, 4));
            m2 = fmaxf(m2, __shfl_xor(m2, 8));
            mx[r] = m2;
        }
        float sm[4] = {0.f, 0.f, 0.f, 0.f};
        #pragma unroll
        for (int nt = 0; nt < 9; nt++)
            #pragma unroll
            for (int r = 0; r < 4; r++) {
                float e = __expf(s[nt][r] - mx[r]);
                s[nt][r] = e;
                sm[r] += e;
            }
        #pragma unroll
        for (int r = 0; r < 4; r++) {
            float s2 = sm[r];
            s2 += __shfl_xor(s2, 1); s2 += __shfl_xor(s2, 2);
            s2 += __shfl_xor(s2, 4); s2 += __shfl_xor(s2, 8);
            sm[r] = 1.0f / s2;
        }
        // P hi write (residual kept in s)
        #pragma unroll
        for (int nt = 0; nt < 9; nt++)
            #pragma unroll
            for (int r = 0; r < 4; r++) {
                float p = s[nt][r] * sm[r];
                unsigned short hh = f2us(p);
                s[nt][r] = p - us2f(hh);
                pscr[(quad * 4 + r) * 184 + nt * 16 + l16] = hh;
            }
        // PV hi
        float4_t o0 = (float4_t){0.f, 0.f, 0.f, 0.f};
        float4_t o1 = (float4_t){0.f, 0.f, 0.f, 0.f};
        #pragma unroll
        for (int ks2 = 0; ks2 < 5; ks2++) {
            short8_t pa = *(short8_t*)(pscr + l16 * 184 + ks2 * 32 + quad * 8);
            short8_t v0 = *(short8_t*)(&vt[l16][ks2 * 32 + quad * 8]);
            short8_t v1 = *(short8_t*)(&vt[16 + l16][ks2 * 32 + quad * 8]);
            o0 = __builtin_amdgcn_mfma_f32_16x16x32_bf16(pa, v0, o0, 0, 0, 0);
            o1 = __builtin_amdgcn_mfma_f32_16x16x32_bf16(pa, v1, o1, 0, 0, 0);
        }
        // P lo write + PV lo (same wave: LDS ops in order; aliasing keeps compiler honest)
        #pragma unroll
        for (int nt = 0; nt < 9; nt++)
            #pragma unroll
            for (int r = 0; r < 4; r++)
                pscr[(quad * 4 + r) * 184 + nt * 16 + l16] = f2us(s[nt][r]);
        #pragma unroll
        for (int ks2 = 0; ks2 < 5; ks2++) {
            short8_t pa = *(short8_t*)(pscr + l16 * 184 + ks2 * 32 + quad * 8);
            short8_t v0 = *(short8_t*)(&vt[l16][ks2 * 32 + quad * 8]);
            short8_t v1 = *(short8_t*)(&vt[16 + l16][ks2 * 32 + quad * 8]);
            o0 = __builtin_amdgcn_mfma_f32_16x16x32_bf16(pa, v0, o0, 0, 0, 0);
            o1 = __builtin_amdgcn_mfma_f32_16x16x32_bf16(pa, v1, o1, 0, 0, 0);
        }
        // O writeback: row = quad*4+r, col = l16 / 16+l16
        size_t obase = (size_t)(tbase + mt * 16 + quad * 4) * INNER + h * HD;
        #pragma unroll
        for (int r = 0; r < 4; r++) {
            ao[obase + (size_t)r * INNER + l16]      = f2us(o0[r]);
            ao[obase + (size_t)r * INNER + 16 + l16] = f2us(o1[r]);
        }
    }
}

#define TM 64
#define TN 64
#define TK 32

// K3: out = ao @ w_out + b_out, scattered through inverse window + roll(+6,+6)
__global__ __launch_bounds__(256) void proj_gemm(
    const unsigned short* __restrict__ ao,   // bf16
    const float* __restrict__ wout,
    const float* __restrict__ bout,
    float* __restrict__ out)
{
    __shared__ float As[TK][TM];
    __shared__ float Bs[TK][TN];
    __shared__ int rowoff[TM];
    const int tid = threadIdx.x;
    const int n0 = blockIdx.x * TN;
    const int m0 = blockIdx.y * TM;
    if (tid < TM) {
        int t = m0 + tid;
        int b = t / (NW * TPW);
        int r = t - b * (NW * TPW);
        int w = r / TPW;
        int i = r - w * TPW;
        int nwy = w >> 3, nww = w & 7;
        int ri = i / WS, ci = i - ri * WS;
        int ys = nwy * WS + ri, xs = nww * WS + ci;
        int yo = ys + DISP; if (yo >= HH) yo -= HH;
        int xo = xs + DISP; if (xo >= WW2) xo -= WW2;
        rowoff[tid] = ((b * HH + yo) * WW2 + xo) * DIM;
    }
    __syncthreads();
    const int tx = tid & 15, ty = tid >> 4;
    const int am = tid >> 2, ad = (tid & 3) << 3;
    const int bk = tid >> 3, bn = (tid & 7) << 3;
    float acc[4][4] = {};
    for (int k0 = 0; k0 < INNER; k0 += TK) {
        ushort8_t a8 = *(const ushort8_t*)(ao + (size_t)(m0 + am) * INNER + k0 + ad);
        float4 b0 = *(const float4*)(wout + (k0 + bk) * DIM + n0 + bn);
        float4 b1 = *(const float4*)(wout + (k0 + bk) * DIM + n0 + bn + 4);
        #pragma unroll
        for (int j = 0; j < 8; j++) As[ad + j][am] = us2f(a8[j]);
        *(float4*)&Bs[bk][bn]     = b0;
        *(float4*)&Bs[bk][bn + 4] = b1;
        __syncthreads();
        #pragma unroll
        for (int kk = 0; kk < TK; kk++) {
            float4 a = *(const float4*)&As[kk][ty * 4];
            float4 b = *(const float4*)&Bs[kk][tx * 4];
            float av[4] = {a.x, a.y, a.z, a.w};
            float bv[4] = {b.x, b.y, b.z, b.w};
            #pragma unroll
            for (int ii = 0; ii < 4; ii++)
                #pragma unroll
                for (int jj = 0; jj < 4; jj++)
                    acc[ii][jj] += av[ii] * bv[jj];
        }
        __syncthreads();
    }
    float4 bo = *(const float4*)(bout + n0 + tx * 4);
    #pragma unroll
    for (int ii = 0; ii < 4; ii++) {
        float4 r;
        r.x = acc[ii][0] + bo.x;
        r.y = acc[ii][1] + bo.y;
        r.z = acc[ii][2] + bo.z;
        r.w = acc[ii][3] + bo.w;
        *(float4*)(out + (size_t)rowoff[ty * 4 + ii] + n0 + tx * 4) = r;
    }
}

extern "C" void kernel_launch(void* const* d_in, const int* in_sizes, int n_in,
                              void* d_out, int out_size, void* d_ws, size_t ws_size,
                              hipStream_t stream) {
    const float* x       = (const float*)d_in[0];
    const int*   pix_map = (const int*)d_in[1];
    const float* wqkv    = (const float*)d_in[2];
    const float* pos_emb = (const float*)d_in[3];
    const float* pix_emb = (const float*)d_in[4];
    const float* wout    = (const float*)d_in[5];
    const float* bout    = (const float*)d_in[6];
    float* out = (float*)d_out;

    unsigned short* ao     = (unsigned short*)d_ws;          // MTOK x 384 bf16
    unsigned short* wqkvT  = ao + (size_t)MTOK * INNER;      // 1152 x 384 bf16

    cast_wqkvT<<<(NQKV * DIM + 255) / 256, 256, 0, stream>>>(wqkv, wqkvT);

    dim3 g2(NW, HEADS, BB);
    fused_attn<<<g2, 256, 0, stream>>>(x, wqkvT, pix_map, pos_emb, pix_emb, ao);

    dim3 g3(DIM / TN, MTOK / TM);
    proj_gemm<<<g3, 256, 0, stream>>>(ao, wout, bout, out);
}

// Round 4
// 746.233 us; speedup vs baseline: 2.1469x; 1.2244x over previous
//
#include <hip/hip_runtime.h>
#include <hip/hip_bf16.h>

#define BB 8
#define HH 96
#define WW2 96
#define DIM 384
#define HEADS 12
#define HD 32
#define WS 12
#define DISP 6
#define NWH 8
#define NWW 8
#define NW 64
#define TPW 144           // tokens per window (12*12)
#define INNER 384         // HEADS*HD
#define NQKV 1152         // 3*INNER
#define MTOK (BB*NW*TPW)  // 73728 tokens total
#define SCALE 0.17677669529663687f

typedef short short8_t __attribute__((ext_vector_type(8)));
typedef float float4_t __attribute__((ext_vector_type(4)));
typedef unsigned short ushort8_t __attribute__((ext_vector_type(8)));
typedef unsigned short ushort4_t __attribute__((ext_vector_type(4)));

__device__ __forceinline__ float us2f(unsigned short u) {
    union { unsigned int u32; float f; } c; c.u32 = ((unsigned int)u) << 16; return c.f;
}
__device__ __forceinline__ unsigned short f2us(float f) {
    union { float f; unsigned int u; } c; c.f = f;
    unsigned int u = c.u;
    u += 0x7FFFu + ((u >> 16) & 1u);   // round-to-nearest-even
    return (unsigned short)(u >> 16);
}

// tiny: wqkvT[n][k] = bf16(wqkv[k][n])
__global__ __launch_bounds__(256) void cast_wqkvT(
    const float* __restrict__ wqkv, unsigned short* __restrict__ wqkvT)
{
    int idx = blockIdx.x * 256 + threadIdx.x;
    if (idx >= NQKV * DIM) return;
    int n = idx / DIM, k = idx - n * DIM;
    wqkvT[idx] = f2us(wqkv[k * NQKV + n]);
}

// Fused per-(b,head,window):  [VERBATIM Round-1 kernel — harness-verified at 538 us]
//   Phase A = MFMA GEMM q|k|v(144x96) = xwin(144x384) @ wT  (bf16 staging, stride-40 pad)
//   Phase B = MFMA attention: QK^T (q/k hi+lo bf16 split), in-register masked softmax,
//             PV (P hi+lo passes vs bf16 V^T). Zero barriers; waves independent.
__global__ __launch_bounds__(256, 2) void fused_attn(
    const float* __restrict__ x,
    const unsigned short* __restrict__ wqkvT,   // [1152][384] bf16
    const int* __restrict__ pix_map,
    const float* __restrict__ pos_emb,          // [23][23]
    const float* __restrict__ pix_emb,          // [2]
    unsigned short* __restrict__ ao)            // [MTOK][INNER] windowed, bf16
{
    __shared__ float qs[TPW][HD + 1];              // scaled q, fp32
    __shared__ float ks[TPW][HD + 1];              // k, fp32
    __shared__ unsigned short vt[HD][168];         // V^T bf16, cols [144,160) zeroed
    __align__(16) __shared__ char uni[23552];      // A: xw[144][40]+wcT[96][40] bf16 ; B: pscr 4x[16][184] bf16
    __shared__ float pos[529];
    __shared__ int   pmv[TPW];
    __shared__ int   rowoff[TPW];

    unsigned short* xw  = (unsigned short*)uni;            // [144][40] bf16
    unsigned short* wcT = (unsigned short*)(uni + 11520);  // [96][40] bf16

    const int tid = threadIdx.x;
    const int w = blockIdx.x, h = blockIdx.y, b = blockIdx.z;
    const int nwy = w >> 3, nww = w & 7;
    const int tbase = (b * NW + w) * TPW;

    if (tid < TPW) {
        int ri = tid / WS, ci = tid - ri * WS;
        int ys = nwy * WS + ri, xs2 = nww * WS + ci;
        int yin = ys + DISP; if (yin >= HH) yin -= HH;
        int xin = xs2 + DISP; if (xin >= WW2) xin -= WW2;
        rowoff[tid] = ((b * HH + yin) * WW2 + xin) * DIM;     // shifted gather
        pmv[tid] = pix_map[(b * HH + ys) * WW2 + xs2];        // UNshifted (ref quirk)
    }
    for (int idx = tid; idx < 529; idx += 256) pos[idx] = pos_emb[idx];
    {   // zero vt pad columns [144,160): 32 rows x 8 dwords = 256 threads
        int zr = tid >> 3, zc = tid & 7;
        *(unsigned int*)(&vt[zr][144 + zc * 2]) = 0u;
    }
    __syncthreads();

    // ---- Phase A: MFMA GEMM, 9x6 grid of 16x16x32 tiles, waves 2x2 ----
    const int wave = tid >> 6, lane = tid & 63;
    const int quad = lane >> 4, l16 = lane & 15;
    const int mw = wave >> 1, nw = wave & 1;
    const int nmt = mw ? 4 : 5;                 // m-tiles: 0..4 / 5..8
    const int mbase = mw * 5, nbase = nw * 3;

    float4_t acc[5][3];
    #pragma unroll
    for (int i = 0; i < 5; i++)
        #pragma unroll
        for (int j = 0; j < 3; j++) acc[i][j] = (float4_t){0.f, 0.f, 0.f, 0.f};

    for (int k0 = 0; k0 < DIM; k0 += 32) {
        for (int idx = tid; idx < 576; idx += 256) {          // xw: 144 rows x 4 chunks
            int r = idx >> 2, qr = idx & 3;
            const float* src = x + rowoff[r] + k0 + qr * 8;
            float4 a = *(const float4*)src;
            float4 c = *(const float4*)(src + 4);
            ushort8_t u;
            u[0] = f2us(a.x); u[1] = f2us(a.y); u[2] = f2us(a.z); u[3] = f2us(a.w);
            u[4] = f2us(c.x); u[5] = f2us(c.y); u[6] = f2us(c.z); u[7] = f2us(c.w);
            *(ushort8_t*)(xw + r * 40 + qr * 8) = u;
        }
        for (int idx = tid; idx < 384; idx += 256) {          // wcT: 96 rows x 4 chunks
            int r = idx >> 2, c = (idx & 3) << 3;
            int s = r >> 5, nn = r & 31;
            int gn = s * INNER + h * HD + nn;
            *(ushort8_t*)(wcT + r * 40 + c) =
                *(const ushort8_t*)(wqkvT + gn * DIM + k0 + c);
        }
        __syncthreads();
        short8_t afr[5], bfr[3];
        #pragma unroll
        for (int j = 0; j < 3; j++)
            bfr[j] = *(short8_t*)(wcT + ((nbase + j) * 16 + l16) * 40 + quad * 8);
        #pragma unroll
        for (int i = 0; i < 5; i++)
            if (i < nmt)
                afr[i] = *(short8_t*)(xw + ((mbase + i) * 16 + l16) * 40 + quad * 8);
        #pragma unroll
        for (int i = 0; i < 5; i++)
            if (i < nmt)
                #pragma unroll
                for (int j = 0; j < 3; j++)
                    acc[i][j] = __builtin_amdgcn_mfma_f32_16x16x32_bf16(
                        afr[i], bfr[j], acc[i][j], 0, 0, 0);
        __syncthreads();
    }
    // C writeback: D col = lane&15, row = quad*4 + reg (m89-verified layout)
    #pragma unroll
    for (int i = 0; i < 5; i++)
        if (i < nmt) {
            int tm = mbase + i;
            #pragma unroll
            for (int j = 0; j < 3; j++) {
                int tn = nbase + j;
                int s = tn >> 1;                    // 0=q, 1=k, 2=v (tile-uniform)
                int cc = ((tn & 1) << 4) | l16;
                if (s == 2) {
                    // v: transposed bf16 store, 4 consecutive cols -> one b64
                    ushort4_t pk;
                    #pragma unroll
                    for (int r = 0; r < 4; r++) pk[r] = f2us(acc[i][j][r]);
                    *(ushort4_t*)(&vt[cc][tm * 16 + quad * 4]) = pk;
                } else {
                    float* dst = (s == 0) ? &qs[0][0] : &ks[0][0];
                    float mul = (s == 0) ? SCALE : 1.0f;
                    #pragma unroll
                    for (int r = 0; r < 4; r++)
                        dst[(tm * 16 + quad * 4 + r) * (HD + 1) + cc] = acc[i][j][r] * mul;
                }
            }
        }
    __syncthreads();

    // ---- Phase B: MFMA attention, wave-private, no barriers ----
    unsigned short* pscr = (unsigned short*)uni + wave * (16 * 184);
    {   // zero pscr pad columns [144,160): 16 rows x 4 qwords = 64 lanes
        int zr = lane >> 2, zc = lane & 3;
        *(unsigned long long*)(pscr + zr * 184 + 144 + zc * 4) = 0ULL;
    }
    const float pe0 = pix_emb[0], pe1 = pix_emb[1];
    const bool ul = (nwy == NWH - 1), lr = (nww == NWW - 1);
    const int mt_start = wave ? (wave * 2 + 1) : 0;   // 0,3,5,7
    const int mt_count = wave ? 2 : 3;

    for (int it = 0; it < mt_count; ++it) {
        const int mt = mt_start + it;
        // Q hi/lo frags
        short8_t qh, ql;
        {
            const float* qrow = &qs[mt * 16 + l16][quad * 8];
            #pragma unroll
            for (int j2 = 0; j2 < 8; j2++) {
                float f = qrow[j2];
                unsigned short hh = f2us(f);
                qh[j2] = (short)hh;
                ql[j2] = (short)f2us(f - us2f(hh));
            }
        }
        // QK^T: 9 n-tiles, K hi/lo per tile, 3 MFMAs each
        float4_t s[9];
        #pragma unroll
        for (int nt = 0; nt < 9; nt++) {
            const float* krow = &ks[nt * 16 + l16][quad * 8];
            short8_t kh, kl;
            #pragma unroll
            for (int j2 = 0; j2 < 8; j2++) {
                float f = krow[j2];
                unsigned short hh = f2us(f);
                kh[j2] = (short)hh;
                kl[j2] = (short)f2us(f - us2f(hh));
            }
            float4_t a = (float4_t){0.f, 0.f, 0.f, 0.f};
            a = __builtin_amdgcn_mfma_f32_16x16x32_bf16(qh, kh, a, 0, 0, 0);
            a = __builtin_amdgcn_mfma_f32_16x16x32_bf16(ql, kh, a, 0, 0, 0);
            a = __builtin_amdgcn_mfma_f32_16x16x32_bf16(qh, kl, a, 0, 0, 0);
            s[nt] = a;
        }
        // masks + bias + rowmax (rows of this lane: i = mt*16 + quad*4 + r, cols j = nt*16+l16)
        const int ib = mt * 16 + quad * 4;
        int riA[4], ciA[4], pmA[4];
        float mx[4];
        #pragma unroll
        for (int r = 0; r < 4; r++) {
            int i = ib + r;
            riA[r] = i / 12; ciA[r] = i - riA[r] * 12;
            pmA[r] = pmv[i];
            mx[r] = -3e38f;
        }
        #pragma unroll
        for (int nt = 0; nt < 9; nt++) {
            int j = nt * 16 + l16;
            int rj = j / 12, cj = j - rj * 12;
            int pj = pmv[j];
            bool jul = (rj >= 6), jlr = (cj >= 6);
            #pragma unroll
            for (int r = 0; r < 4; r++) {
                float a = s[nt][r];
                a += pos[(rj - riA[r] + 11) * 23 + (cj - ciA[r] + 11)];
                a += (pmA[r] * pj) ? pe1 : pe0;
                if (ul && ((riA[r] >= 6) != jul)) a -= 1e30f;
                if (lr && ((ciA[r] >= 6) != jlr)) a -= 1e30f;
                s[nt][r] = a;
                mx[r] = fmaxf(mx[r], a);
            }
        }
        #pragma unroll
        for (int r = 0; r < 4; r++) {
            float m2 = mx[r];
            m2 = fmaxf(m2, __shfl_xor(m2, 1));
            m2 = fmaxf(m2, __shfl_xor(m2, 2));
            m2 = fmaxf(m2, __shfl_xor(m2, 4));
            m2 = fmaxf(m2, __shfl_xor(m2, 8));
            mx[r] = m2;
        }
        float sm[4] = {0.f, 0.f, 0.f, 0.f};
        #pragma unroll
        for (int nt = 0; nt < 9; nt++)
            #pragma unroll
            for (int r = 0; r < 4; r++) {
                float e = __expf(s[nt][r] - mx[r]);
                s[nt][r] = e;
                sm[r] += e;
            }
        #pragma unroll
        for (int r = 0; r < 4; r++) {
            float s2 = sm[r];
            s2 += __shfl_xor(s2, 1); s2 += __shfl_xor(s2, 2);
            s2 += __shfl_xor(s2, 4); s2 += __shfl_xor(s2, 8);
            sm[r] = 1.0f / s2;
        }
        // P hi write (residual kept in s)
        #pragma unroll
        for (int nt = 0; nt < 9; nt++)
            #pragma unroll
            for (int r = 0; r < 4; r++) {
                float p = s[nt][r] * sm[r];
                unsigned short hh = f2us(p);
                s[nt][r] = p - us2f(hh);
                pscr[(quad * 4 + r) * 184 + nt * 16 + l16] = hh;
            }
        // PV hi
        float4_t o0 = (float4_t){0.f, 0.f, 0.f, 0.f};
        float4_t o1 = (float4_t){0.f, 0.f, 0.f, 0.f};
        #pragma unroll
        for (int ks2 = 0; ks2 < 5; ks2++) {
            short8_t pa = *(short8_t*)(pscr + l16 * 184 + ks2 * 32 + quad * 8);
            short8_t v0 = *(short8_t*)(&vt[l16][ks2 * 32 + quad * 8]);
            short8_t v1 = *(short8_t*)(&vt[16 + l16][ks2 * 32 + quad * 8]);
            o0 = __builtin_amdgcn_mfma_f32_16x16x32_bf16(pa, v0, o0, 0, 0, 0);
            o1 = __builtin_amdgcn_mfma_f32_16x16x32_bf16(pa, v1, o1, 0, 0, 0);
        }
        // P lo write + PV lo (same wave: LDS ops in order; aliasing keeps compiler honest)
        #pragma unroll
        for (int nt = 0; nt < 9; nt++)
            #pragma unroll
            for (int r = 0; r < 4; r++)
                pscr[(quad * 4 + r) * 184 + nt * 16 + l16] = f2us(s[nt][r]);
        #pragma unroll
        for (int ks2 = 0; ks2 < 5; ks2++) {
            short8_t pa = *(short8_t*)(pscr + l16 * 184 + ks2 * 32 + quad * 8);
            short8_t v0 = *(short8_t*)(&vt[l16][ks2 * 32 + quad * 8]);
            short8_t v1 = *(short8_t*)(&vt[16 + l16][ks2 * 32 + quad * 8]);
            o0 = __builtin_amdgcn_mfma_f32_16x16x32_bf16(pa, v0, o0, 0, 0, 0);
            o1 = __builtin_amdgcn_mfma_f32_16x16x32_bf16(pa, v1, o1, 0, 0, 0);
        }
        // O writeback: row = quad*4+r, col = l16 / 16+l16
        size_t obase = (size_t)(tbase + mt * 16 + quad * 4) * INNER + h * HD;
        #pragma unroll
        for (int r = 0; r < 4; r++) {
            ao[obase + (size_t)r * INNER + l16]      = f2us(o0[r]);
            ao[obase + (size_t)r * INNER + 16 + l16] = f2us(o1[r]);
        }
    }
}

// K3 (MFMA): out = ao @ wout + b_out, scattered through inverse window + roll(+6,+6).
// wout is read fp32 and split to bf16 hi/lo IN-KERNEL (no extra workspace, no pre-pass).
// M-tile 128, N-tile 64, K step 32; 4 waves in 2x2; per wave 4x2 16x16 tiles, 2 MFMA (hi+lo) each.
__global__ __launch_bounds__(256) void proj_mfma(
    const unsigned short* __restrict__ ao,    // [MTOK][384] bf16
    const float* __restrict__ wout,           // [384][384] fp32, [k][n]
    const float* __restrict__ bout,
    float* __restrict__ out)
{
    __align__(16) __shared__ unsigned short As[128 * 40];  // A rows m, k contiguous
    __align__(16) __shared__ unsigned short Bh[64 * 40];   // B rows n, k contiguous (hi)
    __align__(16) __shared__ unsigned short Bl[64 * 40];   // (lo)
    __shared__ int rowoff[128];
    const int tid = threadIdx.x;
    const int n0 = blockIdx.x * 64;
    const int m0 = blockIdx.y * 128;
    if (tid < 128) {
        int t = m0 + tid;
        int b = t / (NW * TPW);
        int r = t - b * (NW * TPW);
        int w = r / TPW;
        int i = r - w * TPW;
        int nwy = w >> 3, nww = w & 7;
        int ri = i / WS, ci = i - ri * WS;
        int ys = nwy * WS + ri, xs = nww * WS + ci;
        int yo = ys + DISP; if (yo >= HH) yo -= HH;
        int xo = xs + DISP; if (xo >= WW2) xo -= WW2;
        rowoff[tid] = ((b * HH + yo) * WW2 + xo) * DIM;
    }
    __syncthreads();
    const int wave = tid >> 6, lane = tid & 63;
    const int quad = lane >> 4, l16 = lane & 15;
    const int mw = wave >> 1, nw2 = wave & 1;
    const int bn = tid & 63;          // B staging: this thread's n (0..63)
    const int bkb = (tid >> 6) * 8;   // B staging: k-chunk base (0,8,16,24)

    float4_t acc[4][2];
    #pragma unroll
    for (int i = 0; i < 4; i++)
        #pragma unroll
        for (int j = 0; j < 2; j++) acc[i][j] = (float4_t){0.f, 0.f, 0.f, 0.f};

    for (int k0 = 0; k0 < INNER; k0 += 32) {
        for (int idx = tid; idx < 512; idx += 256) {            // As: 128 rows x 4 chunks
            int r = idx >> 2, c = (idx & 3) << 3;
            *(ushort8_t*)(As + r * 40 + c) =
                *(const ushort8_t*)(ao + (size_t)(m0 + r) * INNER + k0 + c);
        }
        // B: 32k x 64n fp32 tile, transpose + hi/lo split. Thread: n=bn, k=k0+bkb+0..7
        #pragma unroll
        for (int j = 0; j < 8; j++) {
            float v = wout[(size_t)(k0 + bkb + j) * DIM + n0 + bn];
            unsigned short hi = f2us(v);
            Bh[bn * 40 + bkb + j] = hi;
            Bl[bn * 40 + bkb + j] = f2us(v - us2f(hi));
        }
        __syncthreads();
        short8_t af[4], bhf[2], blf[2];
        #pragma unroll
        for (int nt = 0; nt < 2; nt++) {
            bhf[nt] = *(short8_t*)(Bh + (nw2 * 32 + nt * 16 + l16) * 40 + quad * 8);
            blf[nt] = *(short8_t*)(Bl + (nw2 * 32 + nt * 16 + l16) * 40 + quad * 8);
        }
        #pragma unroll
        for (int mt = 0; mt < 4; mt++)
            af[mt] = *(short8_t*)(As + (mw * 64 + mt * 16 + l16) * 40 + quad * 8);
        #pragma unroll
        for (int mt = 0; mt < 4; mt++)
            #pragma unroll
            for (int nt = 0; nt < 2; nt++) {
                acc[mt][nt] = __builtin_amdgcn_mfma_f32_16x16x32_bf16(
                    af[mt], bhf[nt], acc[mt][nt], 0, 0, 0);
                acc[mt][nt] = __builtin_amdgcn_mfma_f32_16x16x32_bf16(
                    af[mt], blf[nt], acc[mt][nt], 0, 0, 0);
            }
        __syncthreads();
    }
    // writeback: D col = l16 (n within 16-tile), row = quad*4 + r (m within 16-tile)
    float bo0 = bout[n0 + nw2 * 32 + l16];
    float bo1 = bout[n0 + nw2 * 32 + 16 + l16];
    #pragma unroll
    for (int mt = 0; mt < 4; mt++)
        #pragma unroll
        for (int r = 0; r < 4; r++) {
            int ml = mw * 64 + mt * 16 + quad * 4 + r;
            size_t rb = (size_t)rowoff[ml] + n0 + nw2 * 32;
            out[rb + l16]      = acc[mt][0][r] + bo0;
            out[rb + 16 + l16] = acc[mt][1][r] + bo1;
        }
}

extern "C" void kernel_launch(void* const* d_in, const int* in_sizes, int n_in,
                              void* d_out, int out_size, void* d_ws, size_t ws_size,
                              hipStream_t stream) {
    const float* x       = (const float*)d_in[0];
    const int*   pix_map = (const int*)d_in[1];
    const float* wqkv    = (const float*)d_in[2];
    const float* pos_emb = (const float*)d_in[3];
    const float* pix_emb = (const float*)d_in[4];
    const float* wout    = (const float*)d_in[5];
    const float* bout    = (const float*)d_in[6];
    float* out = (float*)d_out;

    // Workspace layout IDENTICAL to the verified Round-1 kernel.
    unsigned short* ao     = (unsigned short*)d_ws;          // MTOK x 384 bf16
    unsigned short* wqkvT  = ao + (size_t)MTOK * INNER;      // 1152 x 384 bf16

    cast_wqkvT<<<(NQKV * DIM + 255) / 256, 256, 0, stream>>>(wqkv, wqkvT);

    dim3 g2(NW, HEADS, BB);
    fused_attn<<<g2, 256, 0, stream>>>(x, wqkvT, pix_map, pos_emb, pix_emb, ao);

    dim3 g3(DIM / 64, MTOK / 128);
    proj_mfma<<<g3, 256, 0, stream>>>(ao, wout, bout, out);
}